// Round 3
// baseline (960.964 us; speedup 1.0000x reference)
//
#include <hip/hip_runtime.h>

// DeformableSliceGrouped on MI355X — R7: conflict-free frag-order staging,
// B hi-plane only (products ah·bh + al·bh), LDS 32KB -> 3 blocks/CU.
//   kA_mfma: u = w2@(f+pe), q = q_w@(f+pe) via mfma_f32_16x16x32_bf16.
//     Staging writes x directly in B-fragment order: ds_write_b64 2-way (free),
//     ds_read_b128 fully contiguous (zero conflict).  A-frags (hi/lo) from L2.
//   kP_probe re-verifies layout vs fp32 VALU on real data -> fallback kA_gemm.

#define B_   2
#define C_   256
#define Z_   32
#define HW_  2304
#define NSP  73728        // Z_*HW_
#define NBN  147456.0f    // B_*Z_*HW_

typedef unsigned short u16;
typedef unsigned int   u32;
typedef __attribute__((ext_vector_type(8))) short bf16x8;
typedef __attribute__((ext_vector_type(4))) float f32x4;

// ---- module-global scratch (d_ws is never used) ----
__device__ int   g_isf32;
__device__ int   g_use_mfma;
__device__ float g_pe[Z_ * C_];
__device__ __align__(16) float g_wt[C_ * 512];      // [c][row]: 0..255 w2, 256..511 q_w
__device__ __align__(16) u16   g_afrag[32 * 8 * 2 * 64 * 8];  // 512 KB packed A-frags
__device__ int   g_qmax[B_ * Z_ * C_];
__device__ __align__(16) float g_Mt[B_ * Z_ * Z_];  // [b][y][zo]
__device__ float g_bn_sum[C_];
__device__ float g_bn_ssq[C_];
__device__ float g_u[(size_t)B_ * C_ * NSP];        // 151 MB fp32: u = w2 @ (f+pe)

__device__ __forceinline__ u16 f2bf(float f) {
  u32 x = __float_as_uint(f);
  x = x + 0x7fffu + ((x >> 16) & 1u);   // RNE
  return (u16)(x >> 16);
}
__device__ __forceinline__ float bf2f(u16 h) {
  return __uint_as_float(((u32)h) << 16);
}
__device__ __forceinline__ float ldx(const void* p, size_t i, int f32) {
  if (f32) return ((const float*)p)[i];
  return __uint_as_float(((u32)((const u16*)p)[i]) << 16);
}
__device__ __forceinline__ void stx(void* p, size_t i, int f32, float v) {
  if (f32) ((float*)p)[i] = v;
  else     ((u16*)p)[i] = f2bf(v);
}
__device__ __forceinline__ int f2key(float f) {
  int b = __float_as_int(f);
  return b >= 0 ? b : (b ^ 0x7fffffff);
}
__device__ __forceinline__ float key2f(int k) {
  int b = k >= 0 ? k : (k ^ 0x7fffffff);
  return __int_as_float(b);
}
__device__ __forceinline__ float sane(float v) {
  u32 a = __float_as_uint(v) & 0x7fffffffu;
  return (a >= 0x7f800000u) ? 0.f : v;
}
__device__ __forceinline__ float wredmax(float m) {
  m = fmaxf(m, __shfl_xor(m, 1));  m = fmaxf(m, __shfl_xor(m, 2));
  m = fmaxf(m, __shfl_xor(m, 4));  m = fmaxf(m, __shfl_xor(m, 8));
  m = fmaxf(m, __shfl_xor(m, 16)); m = fmaxf(m, __shfl_xor(m, 32));
  return m;
}
__device__ __forceinline__ float wredsum(float s) {
  s += __shfl_xor(s, 1);  s += __shfl_xor(s, 2);  s += __shfl_xor(s, 4);
  s += __shfl_xor(s, 8);  s += __shfl_xor(s, 16); s += __shfl_xor(s, 32);
  return s;
}

// ================= MFMA shared primitives (probe AND main kernel) ==========
// LDS layout = exact B-fragment order (32 KB, hi plane only):
//   byte = frag(j= n>>4, kk= k>>5)*1024 + lane((g= (k>>3)&3)<<4 | (n&15))*16
//          + (i= k&7)*2
// Read back as ds_read_b128 at frag*1024 + lane*16: lane l receives
// x[k = kk*32 + (l>>4)*8 + 0..7][n = j*16 + (l&15)]  == MFMA B-frag layout
// (verified end-to-end by kP_probe in R6; re-verified here).

__device__ __forceinline__ void stage_x(const void* __restrict__ f, int f32,
                                        int b, int z, int ncol0, u16* xs) {
  const int tid = threadIdx.x;
  const int w = tid >> 6, l = tid & 63;
  const int m  = l & 15;          // n & 15
  const int g4 = l >> 4;          // k-quad selector: k0 = 16r + 4*g4
  const size_t fcol = (size_t)ncol0 + (w * 16 + m);
#pragma unroll 4
  for (int r = 0; r < 16; ++r) {
    const int k0 = r * 16 + g4 * 4;
    const float4 pv = *(const float4*)(g_pe + z * C_ + k0);
    const size_t fe = (size_t)(b * C_ + k0) * NSP + fcol;
    float x0, x1, x2, x3;
    if (f32) {
      const float* ff = (const float*)f;
      x0 = ff[fe];
      x1 = ff[fe + (size_t)NSP];
      x2 = ff[fe + 2 * (size_t)NSP];
      x3 = ff[fe + 3 * (size_t)NSP];
    } else {
      x0 = ldx(f, fe, 0);
      x1 = ldx(f, fe + (size_t)NSP, 0);
      x2 = ldx(f, fe + 2 * (size_t)NSP, 0);
      x3 = ldx(f, fe + 3 * (size_t)NSP, 0);
    }
    ushort4 hv;
    hv.x = f2bf(x0 + pv.x);
    hv.y = f2bf(x1 + pv.y);
    hv.z = f2bf(x2 + pv.z);
    hv.w = f2bf(x3 + pv.w);
    // dest: kk = k0>>5 = r>>1 ; g = (k0>>3)&3 = ((r&1)<<1)|(g4>>1) ; i = 4*(g4&1)
    const u32 byte = (u32)(w * 8 + (r >> 1)) * 1024u
                   + (u32)(((((r & 1) << 1) | (g4 >> 1)) << 4) | m) * 16u
                   + (u32)(g4 & 1) * 8u;
    *(ushort4*)((char*)xs + byte) = hv;   // b64, 2 accesses/bank/cyc = free
  }
}

__device__ __forceinline__ bf16x8 read_bfrag(const u16* xs, int j, int kk, int lane) {
  // 64 lanes x contiguous 16B = 1KB linear: zero bank conflicts
  return *(const bf16x8*)(const void*)((const char*)xs +
         ((u32)(j * 8 + kk) * 1024u + (u32)lane * 16u));
}

__device__ __forceinline__ bf16x8 load_afrag(int rs, int kk, int plane, int lane) {
  const size_t off = ((((size_t)(rs * 8 + kk) * 2 + plane) * 64 + lane) * 8);
  return *(const bf16x8*)(const void*)(g_afrag + off);
}

// ------------------------------------------------ K00: input dtype detector
__global__ void k00_detect(const void* f) {
  const int t = threadIdx.x;
  u32 w = ((const u32*)f)[(size_t)t * 9973u];
  u32 e = (w >> 7) & 0xFFu;
  int in = (e >= 90u && e <= 140u) ? 1 : 0;
  for (int o = 1; o < 64; o <<= 1) in += __shfl_xor(in, o);
  if (t == 0) g_isf32 = (in < 40) ? 1 : 0;
}

// ------------------------------------------------ K0: setup
__device__ __forceinline__ void pack_afrag(int row, int k, float val) {
  const int rs = row >> 4, kk = k >> 5, i = k & 7, g = (k >> 3) & 3;
  const int l = (row & 15) | (g << 4);
  u16 hi = f2bf(val);
  u16 lo = f2bf(val - bf2f(hi));
  const size_t u = (((size_t)(rs * 8 + kk) * 2) * 64 + l) * 8 + i;
  g_afrag[u] = hi;
  g_afrag[u + 512] = lo;   // plane offset = 64*8 u16
}

__global__ __launch_bounds__(256) void k0_setup(const void* o_w, const void* v_w,
                                                const void* q_w) {
  const int f32 = g_isf32;
  const int blk = blockIdx.x, t = threadIdx.x;
  if (blk < 256) {
    float acc = 0.f;
    for (int c = 0; c < 256; ++c)
      acc += ldx(o_w, (size_t)blk * 256 + c, f32) * ldx(v_w, (size_t)c * 256 + t, f32);
    g_wt[(size_t)t * 512 + blk] = acc;
    const float qv = ldx(q_w, (size_t)blk * 256 + t, f32);
    g_wt[(size_t)t * 512 + 256 + blk] = qv;
    pack_afrag(blk, t, acc);          // rows 0..255 = w2
    pack_afrag(256 + blk, t, qv);     // rows 256..511 = q_w
  } else {
    const int ch = t;
    const float divf = expf(-(float)(ch >> 1) * (9.210340371976184f / 128.0f));
    for (int z = 0; z < Z_; ++z) {
      float arg = (float)z * divf;
      g_pe[z * 256 + ch] = (ch & 1) ? cosf(arg) : sinf(arg);
    }
    const int init_key = f2key(-1e30f);
    for (int k = t; k < B_ * Z_ * 256; k += 256) g_qmax[k] = init_key;
    g_bn_sum[t] = 0.f;
    g_bn_ssq[t] = 0.f;
  }
}

// ------------------------------------------------ KP: MFMA layout probe
__global__ __launch_bounds__(256) void kP_probe(const void* __restrict__ f) {
  __shared__ u16 xs[16384];
  const int f32 = g_isf32;
  stage_x(f, f32, 0, 0, 0, xs);
  __syncthreads();
  if (threadIdx.x < 64) {
    const int lane = threadIdx.x;
    f32x4 acc = {0.f, 0.f, 0.f, 0.f};
    for (int kk = 0; kk < 8; ++kk) {
      bf16x8 bh = read_bfrag(xs, 0, kk, lane);
      bf16x8 ah = load_afrag(0, kk, 0, lane);
      bf16x8 al = load_afrag(0, kk, 1, lane);
      acc = __builtin_amdgcn_mfma_f32_16x16x32_bf16(ah, bh, acc, 0, 0, 0);
      acc = __builtin_amdgcn_mfma_f32_16x16x32_bf16(al, bh, acc, 0, 0, 0);
    }
    int ok = 1;
    const int col = lane & 15;
#pragma unroll
    for (int reg = 0; reg < 4; ++reg) {
      const int row = (lane >> 4) * 4 + reg;   // rows 0..15 (w2)
      float r0 = 0.f, r1 = 0.f, r2 = 0.f, r3 = 0.f;
      for (int k = 0; k < 256; k += 4) {
        r0 = fmaf(g_wt[(size_t)(k+0) * 512 + row],
                  ldx(f, (size_t)(k+0) * NSP + col, f32) + g_pe[k+0], r0);
        r1 = fmaf(g_wt[(size_t)(k+1) * 512 + row],
                  ldx(f, (size_t)(k+1) * NSP + col, f32) + g_pe[k+1], r1);
        r2 = fmaf(g_wt[(size_t)(k+2) * 512 + row],
                  ldx(f, (size_t)(k+2) * NSP + col, f32) + g_pe[k+2], r2);
        r3 = fmaf(g_wt[(size_t)(k+3) * 512 + row],
                  ldx(f, (size_t)(k+3) * NSP + col, f32) + g_pe[k+3], r3);
      }
      float ref = (r0 + r1) + (r2 + r3);
      ok &= (fabsf(acc[reg] - ref) <= 0.02f + 0.01f * fabsf(ref)) ? 1 : 0;
    }
    ok = __all(ok);
    if (lane == 0) g_use_mfma = ok;
  }
}

// ------------------------------------------------ KA-MFMA: fused dual GEMM
// 2304 blocks = b(2) * z(32) * nchunk(36).  Block: 512 rows x 64 n, K=256.
// Wave w owns rows [w*128, w*128+128): waves 0,1 -> u store; 2,3 -> q maxpool.
__global__ __launch_bounds__(256) void kA_mfma(const void* __restrict__ f) {
  if (!g_use_mfma) return;
  __shared__ u16 xs[16384];          // 32 KB: B-frag-order x (hi plane)
  const int f32 = g_isf32;
  const int id = blockIdx.x;
  const int b = id / 1152;
  const int r2 = id % 1152;
  const int z = r2 / 36;
  const int m = r2 % 36;
  const int ncol0 = z * HW_ + m * 64;
  const int tid = threadIdx.x, w = tid >> 6, lane = tid & 63;

  stage_x(f, f32, b, z, ncol0, xs);
  __syncthreads();

  f32x4 acc[8][4];
  const f32x4 z4 = {0.f, 0.f, 0.f, 0.f};
#pragma unroll
  for (int r = 0; r < 8; ++r)
#pragma unroll
    for (int j = 0; j < 4; ++j) acc[r][j] = z4;

#pragma unroll 2
  for (int kk = 0; kk < 8; ++kk) {
    bf16x8 bh[4];
#pragma unroll
    for (int j = 0; j < 4; ++j) bh[j] = read_bfrag(xs, j, kk, lane);
#pragma unroll
    for (int rsl = 0; rsl < 8; ++rsl) {
      const int rs = w * 8 + rsl;
      bf16x8 ah = load_afrag(rs, kk, 0, lane);
      bf16x8 al = load_afrag(rs, kk, 1, lane);
#pragma unroll
      for (int j = 0; j < 4; ++j) {
        acc[rsl][j] = __builtin_amdgcn_mfma_f32_16x16x32_bf16(ah, bh[j], acc[rsl][j], 0, 0, 0);
        acc[rsl][j] = __builtin_amdgcn_mfma_f32_16x16x32_bf16(al, bh[j], acc[rsl][j], 0, 0, 0);
      }
    }
  }

  if (w < 2) {
    // u rows 0..255: store to g_u
#pragma unroll
    for (int rsl = 0; rsl < 8; ++rsl)
#pragma unroll
      for (int j = 0; j < 4; ++j)
#pragma unroll
        for (int reg = 0; reg < 4; ++reg) {
          const int row = (w * 8 + rsl) * 16 + (lane >> 4) * 4 + reg;
          g_u[(size_t)(b * C_ + row) * NSP + ncol0 + j * 16 + (lane & 15)] =
              acc[rsl][j][reg];
        }
  } else {
    // q rows 0..255: hw-maxpool within this 64-n chunk -> atomicMax
    const int rbase = (b * Z_ + z) * C_;
#pragma unroll
    for (int rsl = 0; rsl < 8; ++rsl)
#pragma unroll
      for (int reg = 0; reg < 4; ++reg) {
        float v = fmaxf(fmaxf(acc[rsl][0][reg], acc[rsl][1][reg]),
                        fmaxf(acc[rsl][2][reg], acc[rsl][3][reg]));
        v = fmaxf(v, __shfl_xor(v, 1));
        v = fmaxf(v, __shfl_xor(v, 2));
        v = fmaxf(v, __shfl_xor(v, 4));
        v = fmaxf(v, __shfl_xor(v, 8));
        if ((lane & 15) == 0)
          atomicMax(&g_qmax[rbase + ((w - 2) * 8 + rsl) * 16 + (lane >> 4) * 4 + reg],
                    f2key(v));
      }
  }
}

// ------------------------------------------------ KA-VALU: R5 fallback (proven)
template<int F32>
__global__ __launch_bounds__(256) void kA_gemm(const void* __restrict__ f) {
  if (g_isf32 != F32) return;
  if (g_use_mfma) return;
  const int bid = blockIdx.x;
  const int k  = bid & 7;
  const int jj = bid >> 3;
  const int T  = k + 8 * (jj >> 3);
  const int g  = jj & 7;
  const int b  = T / 288;
  const int tz = T % 288;
  const int z  = tz / 9;
  const int hc = tz % 9;
  const int t  = threadIdx.x;
  const int n_in_z = hc * 256 + t;
  const size_t fbase = (size_t)(b * C_) * NSP + (size_t)z * HW_ + n_in_z;

  float acc[64];
#pragma unroll
  for (int i = 0; i < 64; ++i) acc[i] = 0.f;

  const float* __restrict__ wtb = g_wt + g * 64;
  const float* __restrict__ pez = g_pe + z * C_;
  for (int c = 0; c < C_; ++c) {
    float fv = ldx(f, fbase + (size_t)c * NSP, F32) + pez[c];
    const float4* __restrict__ w4 = (const float4*)(wtb + (size_t)c * 512);
#pragma unroll
    for (int q = 0; q < 16; ++q) {
      float4 wv = w4[q];
      acc[4*q+0] = fmaf(wv.x, fv, acc[4*q+0]);
      acc[4*q+1] = fmaf(wv.y, fv, acc[4*q+1]);
      acc[4*q+2] = fmaf(wv.z, fv, acc[4*q+2]);
      acc[4*q+3] = fmaf(wv.w, fv, acc[4*q+3]);
    }
  }

  if (g < 4) {
    const size_t obase = (size_t)(b * C_ + g * 64) * NSP + (size_t)z * HW_ + n_in_z;
#pragma unroll
    for (int i = 0; i < 64; ++i)
      g_u[obase + (size_t)i * NSP] = acc[i];
  } else {
    const int rbase = (b * Z_ + z) * C_ + (g - 4) * 64;
#pragma unroll
    for (int i = 0; i < 64; ++i) {
      float mres = wredmax(acc[i]);
      if ((t & 63) == 0) atomicMax(&g_qmax[rbase + i], f2key(mres));
    }
  }
}

// ------------------------------------------------ K2: M build (tiny)
__global__ __launch_bounds__(64) void k2_mbuild(
    const void* offs_w, const void* offs_b,
    const void* attn_w, const void* attn_b) {
  const int f32 = g_isf32;
  const int bz = blockIdx.x;
  const int lane = threadIdx.x;
  float qp[4];
#pragma unroll
  for (int i = 0; i < 4; ++i)
    qp[i] = key2f(g_qmax[bz * 256 + lane * 4 + i]);

  float res[12];
  for (int p = 0; p < 12; ++p) {
    const void* wm = (p < 6) ? offs_w : attn_w;
    const size_t row = (size_t)(p < 6 ? p : p - 6) * 256;
    float s = 0.f;
#pragma unroll
    for (int i = 0; i < 4; ++i) s += qp[i] * ldx(wm, row + lane * 4 + i, f32);
    res[p] = sane(wredsum(s));
  }

  __shared__ float sm[Z_];
  if (lane < Z_) sm[lane] = 0.f;
  __syncthreads();
  if (lane == 0) {
    float att[6], mx = -1e30f;
#pragma unroll
    for (int p = 0; p < 6; ++p) {
      att[p] = sane(res[6 + p] + ldx(attn_b, p, f32));
      mx = fmaxf(mx, att[p]);
    }
    float den = 0.f;
#pragma unroll
    for (int p = 0; p < 6; ++p) { att[p] = expf(att[p] - mx); den += att[p]; }
    float inv = 1.f / den;
#pragma unroll
    for (int p = 0; p < 6; ++p) {
      float a = att[p] * inv;
      float off = sane(res[p] + ldx(offs_b, p, f32));
      off = fminf(fmaxf(off, 0.f), 31.f);
      float lo = floorf(off), hi = ceilf(off), fr = off - lo;
      int il = min(max((int)lo, 0), 31);
      int ih = min(max((int)hi, 0), 31);
      sm[il] += a * (1.f - fr);
      sm[ih] += a * fr;
    }
  }
  __syncthreads();
  if (lane < Z_) g_Mt[((bz >> 5) * Z_ + lane) * Z_ + (bz & 31)] = sm[lane];
}

// ------------------------------------------------ KB: z-mix of u + BN stats
__global__ __launch_bounds__(256) void kB_mix(void* outp) {
  const int f32 = g_isf32;
  const int id = blockIdx.x;
  const int b = id / 2304;
  const int rem = id % 2304;
  const int o = rem / 9;
  const int hc = rem % 9;
  const int hw = hc * 256 + threadIdx.x;
  const size_t base = (size_t)(b * C_ + o) * NSP + hw;

  float a[Z_];
#pragma unroll
  for (int zo = 0; zo < Z_; ++zo) a[zo] = 0.f;

  for (int y = 0; y < Z_; ++y) {
    float uv = g_u[base + (size_t)y * HW_];
    const float4* __restrict__ m4 = (const float4*)(g_Mt + (size_t)(b * Z_ + y) * Z_);
#pragma unroll
    for (int q = 0; q < 8; ++q) {
      float4 mv = m4[q];
      a[4*q+0] = fmaf(mv.x, uv, a[4*q+0]);
      a[4*q+1] = fmaf(mv.y, uv, a[4*q+1]);
      a[4*q+2] = fmaf(mv.z, uv, a[4*q+2]);
      a[4*q+3] = fmaf(mv.w, uv, a[4*q+3]);
    }
  }

  float s = 0.f, ss = 0.f;
#pragma unroll
  for (int zo = 0; zo < Z_; ++zo) {
    float v = sane(a[zo]);
    stx(outp, base + (size_t)zo * HW_, f32, v);
    s += v;  ss += v * v;
  }
  s = wredsum(s);
  ss = wredsum(ss);
  if ((threadIdx.x & 63) == 0) {
    atomicAdd(&g_bn_sum[o], s);
    atomicAdd(&g_bn_ssq[o], ss);
  }
}

// ------------------------------------------------ K5: BN + residual (float4)
__global__ __launch_bounds__(256) void k5_final(
    const void* f, void* outp, const void* gamma, const void* beta) {
  const int f32 = g_isf32;
  const size_t e4 = ((size_t)blockIdx.x * 256 + threadIdx.x) * 4;
  const int o = (int)((e4 / NSP) & 255);
  const float mean = g_bn_sum[o] * (1.f / NBN);
  const float var = fmaxf(g_bn_ssq[o] * (1.f / NBN) - mean * mean, 0.f);
  const float rstd = rsqrtf(var + 1e-5f);
  const float sc = ldx(gamma, o, f32) * rstd;
  const float sh = ldx(beta, o, f32) - mean * sc;
  if (f32) {
    float4 ov = *(float4*)((float*)outp + e4);
    const float4 fv = *(const float4*)((const float*)f + e4);
    ov.x = sane(ov.x * sc + sh + fv.x);
    ov.y = sane(ov.y * sc + sh + fv.y);
    ov.z = sane(ov.z * sc + sh + fv.z);
    ov.w = sane(ov.w * sc + sh + fv.w);
    *(float4*)((float*)outp + e4) = ov;
  } else {
#pragma unroll
    for (int i = 0; i < 4; ++i) {
      float v = sane(ldx(outp, e4 + i, 0) * sc + sh + ldx(f, e4 + i, 0));
      stx(outp, e4 + i, 0, v);
    }
  }
}

// ------------------------------------------------ launch
extern "C" void kernel_launch(void* const* d_in, const int* in_sizes, int n_in,
                              void* d_out, int out_size, void* d_ws, size_t ws_size,
                              hipStream_t stream)
{
  (void)in_sizes; (void)n_in; (void)out_size; (void)d_ws; (void)ws_size;
  const void* f      = d_in[0];
  const void* q_w    = d_in[1];
  const void* v_w    = d_in[2];
  const void* o_w    = d_in[3];
  const void* offs_w = d_in[4];
  const void* offs_b = d_in[5];
  const void* attn_w = d_in[6];
  const void* attn_b = d_in[7];
  const void* gamma  = d_in[8];
  const void* beta   = d_in[9];

  k00_detect<<<1, 64, 0, stream>>>(f);
  k0_setup<<<257, 256, 0, stream>>>(o_w, v_w, q_w);
  kP_probe<<<1, 256, 0, stream>>>(f);
  kA_mfma<<<2304, 256, 0, stream>>>(f);
  kA_gemm<1><<<4608, 256, 0, stream>>>(f);   // fallback, gated on g_use_mfma
  kA_gemm<0><<<4608, 256, 0, stream>>>(f);
  k2_mbuild<<<64, 64, 0, stream>>>(offs_w, offs_b, attn_w, attn_b);
  kB_mix<<<4608, 256, 0, stream>>>(d_out);
  k5_final<<<36864, 256, 0, stream>>>(f, d_out, gamma, beta);
}

// Round 4
// 650.291 us; speedup vs baseline: 1.4777x; 1.4777x over previous
//
#include <hip/hip_runtime.h>

// DeformableSliceGrouped on MI355X — R8: occupancy fix.
//   kA_mfma: 512 threads (8 waves), wave owns 4 rs (64 rows) -> acc 64 VGPR,
//     __launch_bounds__(512,4) caps VGPR at 128 -> 4 waves/SIMD (2 blk/CU).
//     Staging = R6's proven pattern: coalesced dwordx4 f-loads, scalar u16
//     LDS writes into n-major XOR-swizzled layout (conflicts ~7us, accepted).
//     B hi-plane only (ah·bh + al·bh), 32 KB LDS.
//   kP_probe re-verifies layout vs fp32 VALU on real data -> fallback kA_gemm.

#define B_   2
#define C_   256
#define Z_   32
#define HW_  2304
#define NSP  73728        // Z_*HW_
#define NBN  147456.0f    // B_*Z_*HW_

typedef unsigned short u16;
typedef unsigned int   u32;
typedef __attribute__((ext_vector_type(8))) short bf16x8;
typedef __attribute__((ext_vector_type(4))) float f32x4;

// ---- module-global scratch (d_ws is never used) ----
__device__ int   g_isf32;
__device__ int   g_use_mfma;
__device__ float g_pe[Z_ * C_];
__device__ __align__(16) float g_wt[C_ * 512];      // [c][row]: 0..255 w2, 256..511 q_w
__device__ __align__(16) u16   g_afrag[32 * 8 * 2 * 64 * 8];  // 512 KB packed A-frags
__device__ int   g_qmax[B_ * Z_ * C_];
__device__ __align__(16) float g_Mt[B_ * Z_ * Z_];  // [b][y][zo]
__device__ float g_bn_sum[C_];
__device__ float g_bn_ssq[C_];
__device__ float g_u[(size_t)B_ * C_ * NSP];        // 151 MB fp32: u = w2 @ (f+pe)

__device__ __forceinline__ u16 f2bf(float f) {
  u32 x = __float_as_uint(f);
  x = x + 0x7fffu + ((x >> 16) & 1u);   // RNE
  return (u16)(x >> 16);
}
__device__ __forceinline__ float bf2f(u16 h) {
  return __uint_as_float(((u32)h) << 16);
}
__device__ __forceinline__ float ldx(const void* p, size_t i, int f32) {
  if (f32) return ((const float*)p)[i];
  return __uint_as_float(((u32)((const u16*)p)[i]) << 16);
}
__device__ __forceinline__ void stx(void* p, size_t i, int f32, float v) {
  if (f32) ((float*)p)[i] = v;
  else     ((u16*)p)[i] = f2bf(v);
}
__device__ __forceinline__ int f2key(float f) {
  int b = __float_as_int(f);
  return b >= 0 ? b : (b ^ 0x7fffffff);
}
__device__ __forceinline__ float key2f(int k) {
  int b = k >= 0 ? k : (k ^ 0x7fffffff);
  return __int_as_float(b);
}
__device__ __forceinline__ float sane(float v) {
  u32 a = __float_as_uint(v) & 0x7fffffffu;
  return (a >= 0x7f800000u) ? 0.f : v;
}
__device__ __forceinline__ float wredmax(float m) {
  m = fmaxf(m, __shfl_xor(m, 1));  m = fmaxf(m, __shfl_xor(m, 2));
  m = fmaxf(m, __shfl_xor(m, 4));  m = fmaxf(m, __shfl_xor(m, 8));
  m = fmaxf(m, __shfl_xor(m, 16)); m = fmaxf(m, __shfl_xor(m, 32));
  return m;
}
__device__ __forceinline__ float wredsum(float s) {
  s += __shfl_xor(s, 1);  s += __shfl_xor(s, 2);  s += __shfl_xor(s, 4);
  s += __shfl_xor(s, 8);  s += __shfl_xor(s, 16); s += __shfl_xor(s, 32);
  return s;
}

// ================= MFMA shared primitives (probe AND main kernel) ==========
// LDS: n-major XOR-swizzled, hi plane only (32 KB):
//   byte(n,k) = n*512 + k*2, XOR ((n&15)<<4)          [R6 HW-verified layout]
// Staged by 512 threads: wave w(0..7), lane l: k = r*32 + w*4 + (l>>4),
//   n = (l&15)*4 + 0..3  -> dwordx4 global load (256B/16-lane group), 4 u16 writes.

__device__ __forceinline__ void stage_x(const void* __restrict__ f, int f32,
                                        int b, int z, int ncol0, u16* xs) {
  const int tid = threadIdx.x;
  const int w = tid >> 6, l = tid & 63;
  const int n0 = (l & 15) * 4;
  const int g = l >> 4;
#pragma unroll
  for (int r = 0; r < 8; ++r) {
    const int k = r * 32 + w * 4 + g;
    const float pv = g_pe[z * C_ + k];
    const size_t fe = (size_t)(b * C_ + k) * NSP + ncol0 + n0;
    float x0, x1, x2, x3;
    if (f32) {
      const float4 v = *(const float4*)((const float*)f + fe);
      x0 = v.x; x1 = v.y; x2 = v.z; x3 = v.w;
    } else {
      x0 = ldx(f, fe + 0, 0); x1 = ldx(f, fe + 1, 0);
      x2 = ldx(f, fe + 2, 0); x3 = ldx(f, fe + 3, 0);
    }
    x0 += pv; x1 += pv; x2 += pv; x3 += pv;
#pragma unroll
    for (int e = 0; e < 4; ++e) {
      const float xv = (e == 0) ? x0 : (e == 1) ? x1 : (e == 2) ? x2 : x3;
      const int n = n0 + e;
      u32 byte = (u32)n * 512u + (u32)k * 2u;
      byte ^= (u32)(n & 15) << 4;
      xs[byte >> 1] = f2bf(xv);
    }
  }
}

// B fragment: lane l supplies B[k = kk*32 + 8*(l>>4) + i][n = j*16 + (l&15)].
__device__ __forceinline__ bf16x8 read_bfrag(const u16* xs, int j, int kk, int lane) {
  const int n = j * 16 + (lane & 15);
  u32 byte = (u32)n * 512u + (u32)kk * 64u + (u32)(lane >> 4) * 16u;
  byte ^= (u32)(n & 15) << 4;
  return *(const bf16x8*)(const void*)((const char*)xs + byte);
}

__device__ __forceinline__ bf16x8 load_afrag(int rs, int kk, int plane, int lane) {
  const size_t off = ((((size_t)(rs * 8 + kk) * 2 + plane) * 64 + lane) * 8);
  return *(const bf16x8*)(const void*)(g_afrag + off);
}

// ------------------------------------------------ K00: input dtype detector
__global__ void k00_detect(const void* f) {
  const int t = threadIdx.x;
  u32 w = ((const u32*)f)[(size_t)t * 9973u];
  u32 e = (w >> 7) & 0xFFu;
  int in = (e >= 90u && e <= 140u) ? 1 : 0;
  for (int o = 1; o < 64; o <<= 1) in += __shfl_xor(in, o);
  if (t == 0) g_isf32 = (in < 40) ? 1 : 0;
}

// ------------------------------------------------ K0: setup
__device__ __forceinline__ void pack_afrag(int row, int k, float val) {
  const int rs = row >> 4, kk = k >> 5, i = k & 7, g = (k >> 3) & 3;
  const int l = (row & 15) | (g << 4);
  u16 hi = f2bf(val);
  u16 lo = f2bf(val - bf2f(hi));
  const size_t u = (((size_t)(rs * 8 + kk) * 2) * 64 + l) * 8 + i;
  g_afrag[u] = hi;
  g_afrag[u + 512] = lo;   // plane offset = 64*8 u16
}

__global__ __launch_bounds__(256) void k0_setup(const void* o_w, const void* v_w,
                                                const void* q_w) {
  const int f32 = g_isf32;
  const int blk = blockIdx.x, t = threadIdx.x;
  if (blk < 256) {
    float acc = 0.f;
    for (int c = 0; c < 256; ++c)
      acc += ldx(o_w, (size_t)blk * 256 + c, f32) * ldx(v_w, (size_t)c * 256 + t, f32);
    g_wt[(size_t)t * 512 + blk] = acc;
    const float qv = ldx(q_w, (size_t)blk * 256 + t, f32);
    g_wt[(size_t)t * 512 + 256 + blk] = qv;
    pack_afrag(blk, t, acc);          // rows 0..255 = w2
    pack_afrag(256 + blk, t, qv);     // rows 256..511 = q_w
  } else {
    const int ch = t;
    const float divf = expf(-(float)(ch >> 1) * (9.210340371976184f / 128.0f));
    for (int z = 0; z < Z_; ++z) {
      float arg = (float)z * divf;
      g_pe[z * 256 + ch] = (ch & 1) ? cosf(arg) : sinf(arg);
    }
    const int init_key = f2key(-1e30f);
    for (int k = t; k < B_ * Z_ * 256; k += 256) g_qmax[k] = init_key;
    g_bn_sum[t] = 0.f;
    g_bn_ssq[t] = 0.f;
  }
}

// ------------------------------------------------ KP: MFMA layout probe
__global__ __launch_bounds__(512) void kP_probe(const void* __restrict__ f) {
  __shared__ u16 xs[16384];
  const int f32 = g_isf32;
  stage_x(f, f32, 0, 0, 0, xs);
  __syncthreads();
  if (threadIdx.x < 64) {
    const int lane = threadIdx.x;
    f32x4 acc = {0.f, 0.f, 0.f, 0.f};
    for (int kk = 0; kk < 8; ++kk) {
      bf16x8 bh = read_bfrag(xs, 0, kk, lane);
      bf16x8 ah = load_afrag(0, kk, 0, lane);
      bf16x8 al = load_afrag(0, kk, 1, lane);
      acc = __builtin_amdgcn_mfma_f32_16x16x32_bf16(ah, bh, acc, 0, 0, 0);
      acc = __builtin_amdgcn_mfma_f32_16x16x32_bf16(al, bh, acc, 0, 0, 0);
    }
    int ok = 1;
    const int col = lane & 15;
#pragma unroll
    for (int reg = 0; reg < 4; ++reg) {
      const int row = (lane >> 4) * 4 + reg;   // rows 0..15 (w2)
      float r0 = 0.f, r1 = 0.f, r2 = 0.f, r3 = 0.f;
      for (int k = 0; k < 256; k += 4) {
        r0 = fmaf(g_wt[(size_t)(k+0) * 512 + row],
                  ldx(f, (size_t)(k+0) * NSP + col, f32) + g_pe[k+0], r0);
        r1 = fmaf(g_wt[(size_t)(k+1) * 512 + row],
                  ldx(f, (size_t)(k+1) * NSP + col, f32) + g_pe[k+1], r1);
        r2 = fmaf(g_wt[(size_t)(k+2) * 512 + row],
                  ldx(f, (size_t)(k+2) * NSP + col, f32) + g_pe[k+2], r2);
        r3 = fmaf(g_wt[(size_t)(k+3) * 512 + row],
                  ldx(f, (size_t)(k+3) * NSP + col, f32) + g_pe[k+3], r3);
      }
      float ref = (r0 + r1) + (r2 + r3);
      ok &= (fabsf(acc[reg] - ref) <= 0.02f + 0.01f * fabsf(ref)) ? 1 : 0;
    }
    ok = __all(ok);
    if (lane == 0) g_use_mfma = ok;
  }
}

// ------------------------------------------------ KA-MFMA: fused dual GEMM
// 2304 blocks x 512 threads = b(2) * z(32) * nchunk(36).  Block: 512 rows x 64 n.
// Wave w (0..7) owns rs = w*4..w*4+3.  w<4 -> u rows (store); w>=4 -> q (maxpool).
__global__ __launch_bounds__(512, 4) void kA_mfma(const void* __restrict__ f) {
  if (!g_use_mfma) return;
  __shared__ u16 xs[16384];          // 32 KB: n-major XOR-swizzled x (hi plane)
  const int f32 = g_isf32;
  const int id = blockIdx.x;
  const int b = id / 1152;
  const int r2 = id % 1152;
  const int z = r2 / 36;
  const int m = r2 % 36;
  const int ncol0 = z * HW_ + m * 64;
  const int tid = threadIdx.x, w = tid >> 6, lane = tid & 63;

  stage_x(f, f32, b, z, ncol0, xs);
  __syncthreads();

  f32x4 acc[4][4];
  const f32x4 z4 = {0.f, 0.f, 0.f, 0.f};
#pragma unroll
  for (int r = 0; r < 4; ++r)
#pragma unroll
    for (int j = 0; j < 4; ++j) acc[r][j] = z4;

#pragma unroll 2
  for (int kk = 0; kk < 8; ++kk) {
    bf16x8 bh[4];
#pragma unroll
    for (int j = 0; j < 4; ++j) bh[j] = read_bfrag(xs, j, kk, lane);
#pragma unroll
    for (int rsl = 0; rsl < 4; ++rsl) {
      const int rs = w * 4 + rsl;
      bf16x8 ah = load_afrag(rs, kk, 0, lane);
      bf16x8 al = load_afrag(rs, kk, 1, lane);
#pragma unroll
      for (int j = 0; j < 4; ++j) {
        acc[rsl][j] = __builtin_amdgcn_mfma_f32_16x16x32_bf16(ah, bh[j], acc[rsl][j], 0, 0, 0);
        acc[rsl][j] = __builtin_amdgcn_mfma_f32_16x16x32_bf16(al, bh[j], acc[rsl][j], 0, 0, 0);
      }
    }
  }

  if (w < 4) {
    // u rows (w*4+rsl)*16 + (lane>>4)*4 + reg  (0..255): store to g_u
#pragma unroll
    for (int rsl = 0; rsl < 4; ++rsl)
#pragma unroll
      for (int j = 0; j < 4; ++j)
#pragma unroll
        for (int reg = 0; reg < 4; ++reg) {
          const int row = (w * 4 + rsl) * 16 + (lane >> 4) * 4 + reg;
          g_u[(size_t)(b * C_ + row) * NSP + ncol0 + j * 16 + (lane & 15)] =
              acc[rsl][j][reg];
        }
  } else {
    // q rows ((w-4)*4+rsl)*16 + ... (0..255): hw-maxpool in chunk -> atomicMax
    const int rbase = (b * Z_ + z) * C_;
#pragma unroll
    for (int rsl = 0; rsl < 4; ++rsl)
#pragma unroll
      for (int reg = 0; reg < 4; ++reg) {
        float v = fmaxf(fmaxf(acc[rsl][0][reg], acc[rsl][1][reg]),
                        fmaxf(acc[rsl][2][reg], acc[rsl][3][reg]));
        v = fmaxf(v, __shfl_xor(v, 1));
        v = fmaxf(v, __shfl_xor(v, 2));
        v = fmaxf(v, __shfl_xor(v, 4));
        v = fmaxf(v, __shfl_xor(v, 8));
        if ((lane & 15) == 0)
          atomicMax(&g_qmax[rbase + ((w - 4) * 4 + rsl) * 16 + (lane >> 4) * 4 + reg],
                    f2key(v));
      }
  }
}

// ------------------------------------------------ KA-VALU: R5 fallback (proven)
template<int F32>
__global__ __launch_bounds__(256) void kA_gemm(const void* __restrict__ f) {
  if (g_isf32 != F32) return;
  if (g_use_mfma) return;
  const int bid = blockIdx.x;
  const int k  = bid & 7;
  const int jj = bid >> 3;
  const int T  = k + 8 * (jj >> 3);
  const int g  = jj & 7;
  const int b  = T / 288;
  const int tz = T % 288;
  const int z  = tz / 9;
  const int hc = tz % 9;
  const int t  = threadIdx.x;
  const int n_in_z = hc * 256 + t;
  const size_t fbase = (size_t)(b * C_) * NSP + (size_t)z * HW_ + n_in_z;

  float acc[64];
#pragma unroll
  for (int i = 0; i < 64; ++i) acc[i] = 0.f;

  const float* __restrict__ wtb = g_wt + g * 64;
  const float* __restrict__ pez = g_pe + z * C_;
  for (int c = 0; c < C_; ++c) {
    float fv = ldx(f, fbase + (size_t)c * NSP, F32) + pez[c];
    const float4* __restrict__ w4 = (const float4*)(wtb + (size_t)c * 512);
#pragma unroll
    for (int q = 0; q < 16; ++q) {
      float4 wv = w4[q];
      acc[4*q+0] = fmaf(wv.x, fv, acc[4*q+0]);
      acc[4*q+1] = fmaf(wv.y, fv, acc[4*q+1]);
      acc[4*q+2] = fmaf(wv.z, fv, acc[4*q+2]);
      acc[4*q+3] = fmaf(wv.w, fv, acc[4*q+3]);
    }
  }

  if (g < 4) {
    const size_t obase = (size_t)(b * C_ + g * 64) * NSP + (size_t)z * HW_ + n_in_z;
#pragma unroll
    for (int i = 0; i < 64; ++i)
      g_u[obase + (size_t)i * NSP] = acc[i];
  } else {
    const int rbase = (b * Z_ + z) * C_ + (g - 4) * 64;
#pragma unroll
    for (int i = 0; i < 64; ++i) {
      float mres = wredmax(acc[i]);
      if ((t & 63) == 0) atomicMax(&g_qmax[rbase + i], f2key(mres));
    }
  }
}

// ------------------------------------------------ K2: M build (tiny)
__global__ __launch_bounds__(64) void k2_mbuild(
    const void* offs_w, const void* offs_b,
    const void* attn_w, const void* attn_b) {
  const int f32 = g_isf32;
  const int bz = blockIdx.x;
  const int lane = threadIdx.x;
  float qp[4];
#pragma unroll
  for (int i = 0; i < 4; ++i)
    qp[i] = key2f(g_qmax[bz * 256 + lane * 4 + i]);

  float res[12];
  for (int p = 0; p < 12; ++p) {
    const void* wm = (p < 6) ? offs_w : attn_w;
    const size_t row = (size_t)(p < 6 ? p : p - 6) * 256;
    float s = 0.f;
#pragma unroll
    for (int i = 0; i < 4; ++i) s += qp[i] * ldx(wm, row + lane * 4 + i, f32);
    res[p] = sane(wredsum(s));
  }

  __shared__ float sm[Z_];
  if (lane < Z_) sm[lane] = 0.f;
  __syncthreads();
  if (lane == 0) {
    float att[6], mx = -1e30f;
#pragma unroll
    for (int p = 0; p < 6; ++p) {
      att[p] = sane(res[6 + p] + ldx(attn_b, p, f32));
      mx = fmaxf(mx, att[p]);
    }
    float den = 0.f;
#pragma unroll
    for (int p = 0; p < 6; ++p) { att[p] = expf(att[p] - mx); den += att[p]; }
    float inv = 1.f / den;
#pragma unroll
    for (int p = 0; p < 6; ++p) {
      float a = att[p] * inv;
      float off = sane(res[p] + ldx(offs_b, p, f32));
      off = fminf(fmaxf(off, 0.f), 31.f);
      float lo = floorf(off), hi = ceilf(off), fr = off - lo;
      int il = min(max((int)lo, 0), 31);
      int ih = min(max((int)hi, 0), 31);
      sm[il] += a * (1.f - fr);
      sm[ih] += a * fr;
    }
  }
  __syncthreads();
  if (lane < Z_) g_Mt[((bz >> 5) * Z_ + lane) * Z_ + (bz & 31)] = sm[lane];
}

// ------------------------------------------------ KB: z-mix of u + BN stats
__global__ __launch_bounds__(256) void kB_mix(void* outp) {
  const int f32 = g_isf32;
  const int id = blockIdx.x;
  const int b = id / 2304;
  const int rem = id % 2304;
  const int o = rem / 9;
  const int hc = rem % 9;
  const int hw = hc * 256 + threadIdx.x;
  const size_t base = (size_t)(b * C_ + o) * NSP + hw;

  float a[Z_];
#pragma unroll
  for (int zo = 0; zo < Z_; ++zo) a[zo] = 0.f;

  for (int y = 0; y < Z_; ++y) {
    float uv = g_u[base + (size_t)y * HW_];
    const float4* __restrict__ m4 = (const float4*)(g_Mt + (size_t)(b * Z_ + y) * Z_);
#pragma unroll
    for (int q = 0; q < 8; ++q) {
      float4 mv = m4[q];
      a[4*q+0] = fmaf(mv.x, uv, a[4*q+0]);
      a[4*q+1] = fmaf(mv.y, uv, a[4*q+1]);
      a[4*q+2] = fmaf(mv.z, uv, a[4*q+2]);
      a[4*q+3] = fmaf(mv.w, uv, a[4*q+3]);
    }
  }

  float s = 0.f, ss = 0.f;
#pragma unroll
  for (int zo = 0; zo < Z_; ++zo) {
    float v = sane(a[zo]);
    stx(outp, base + (size_t)zo * HW_, f32, v);
    s += v;  ss += v * v;
  }
  s = wredsum(s);
  ss = wredsum(ss);
  if ((threadIdx.x & 63) == 0) {
    atomicAdd(&g_bn_sum[o], s);
    atomicAdd(&g_bn_ssq[o], ss);
  }
}

// ------------------------------------------------ K5: BN + residual (float4)
__global__ __launch_bounds__(256) void k5_final(
    const void* f, void* outp, const void* gamma, const void* beta) {
  const int f32 = g_isf32;
  const size_t e4 = ((size_t)blockIdx.x * 256 + threadIdx.x) * 4;
  const int o = (int)((e4 / NSP) & 255);
  const float mean = g_bn_sum[o] * (1.f / NBN);
  const float var = fmaxf(g_bn_ssq[o] * (1.f / NBN) - mean * mean, 0.f);
  const float rstd = rsqrtf(var + 1e-5f);
  const float sc = ldx(gamma, o, f32) * rstd;
  const float sh = ldx(beta, o, f32) - mean * sc;
  if (f32) {
    float4 ov = *(float4*)((float*)outp + e4);
    const float4 fv = *(const float4*)((const float*)f + e4);
    ov.x = sane(ov.x * sc + sh + fv.x);
    ov.y = sane(ov.y * sc + sh + fv.y);
    ov.z = sane(ov.z * sc + sh + fv.z);
    ov.w = sane(ov.w * sc + sh + fv.w);
    *(float4*)((float*)outp + e4) = ov;
  } else {
#pragma unroll
    for (int i = 0; i < 4; ++i) {
      float v = sane(ldx(outp, e4 + i, 0) * sc + sh + ldx(f, e4 + i, 0));
      stx(outp, e4 + i, 0, v);
    }
  }
}

// ------------------------------------------------ launch
extern "C" void kernel_launch(void* const* d_in, const int* in_sizes, int n_in,
                              void* d_out, int out_size, void* d_ws, size_t ws_size,
                              hipStream_t stream)
{
  (void)in_sizes; (void)n_in; (void)out_size; (void)d_ws; (void)ws_size;
  const void* f      = d_in[0];
  const void* q_w    = d_in[1];
  const void* v_w    = d_in[2];
  const void* o_w    = d_in[3];
  const void* offs_w = d_in[4];
  const void* offs_b = d_in[5];
  const void* attn_w = d_in[6];
  const void* attn_b = d_in[7];
  const void* gamma  = d_in[8];
  const void* beta   = d_in[9];

  k00_detect<<<1, 64, 0, stream>>>(f);
  k0_setup<<<257, 256, 0, stream>>>(o_w, v_w, q_w);
  kP_probe<<<1, 512, 0, stream>>>(f);
  kA_mfma<<<2304, 512, 0, stream>>>(f);
  kA_gemm<1><<<4608, 256, 0, stream>>>(f);   // fallback, gated on g_use_mfma
  kA_gemm<0><<<4608, 256, 0, stream>>>(f);
  k2_mbuild<<<64, 64, 0, stream>>>(offs_w, offs_b, attn_w, attn_b);
  kB_mix<<<4608, 256, 0, stream>>>(d_out);
  k5_final<<<36864, 256, 0, stream>>>(f, d_out, gamma, beta);
}